// Round 15
// baseline (236.257 us; speedup 1.0000x reference)
//
#include <hip/hip_runtime.h>
#include <stdint.h>

#define SB 2048
#define DB 1024
#define NHB 16
#define DHB 64

typedef __attribute__((ext_vector_type(8))) short short8;
typedef __attribute__((ext_vector_type(4))) short short4v;
typedef __attribute__((ext_vector_type(4))) float f32x4;

// scale 1/8 folded with log2(e): exp(s/8) = exp2(s * 0.125*log2e)
#define SC2 0.18033688011112042f

__device__ __forceinline__ unsigned short f2bf(float f) {
  union { float f; uint32_t u; } v; v.f = f;
  uint32_t u = v.u;
  return (unsigned short)((u + 0x7FFFu + ((u >> 16) & 1u)) >> 16);
}

// 8 fp32 -> 8 bf16 (RNE) via v_cvt_pk_bf16_f32 (T12 recipe)
__device__ __forceinline__ short8 cvt8(const float* p) {
  f32x4 a = *(const f32x4*)p;
  f32x4 b = *(const f32x4*)(p + 4);
  union { uint32_t u[4]; short8 s; } o;
  asm("v_cvt_pk_bf16_f32 %0, %1, %2" : "=v"(o.u[0]) : "v"(a[0]), "v"(a[1]));
  asm("v_cvt_pk_bf16_f32 %0, %1, %2" : "=v"(o.u[1]) : "v"(a[2]), "v"(a[3]));
  asm("v_cvt_pk_bf16_f32 %0, %1, %2" : "=v"(o.u[2]) : "v"(b[0]), "v"(b[1]));
  asm("v_cvt_pk_bf16_f32 %0, %1, %2" : "=v"(o.u[3]) : "v"(b[2]), "v"(b[3]));
  return o.s;
}

__device__ __forceinline__ void gld16(const void* g, void* l) {
  __builtin_amdgcn_global_load_lds(
      (const __attribute__((address_space(1))) void*)g,
      (__attribute__((address_space(3))) void*)l, 16, 0, 0);
}

__device__ __forceinline__ int xcd_swz(int bid, int nwg) {
  return (bid & 7) * (nwg >> 3) + (bid >> 3);   // bijective when nwg % 8 == 0
}

// ------- K1: fused convert+GEMM (fp32 in, bf16 out), 128x128, BK=64 --------
// z=0,1: head-split (Q/K). z=2: V-transpose. z=3: Wo column-permute blocks.
struct PGArgs {
  const float* A[3];
  const float* B[3];
  unsigned short* O[3];
  int mode[3];
  const float* Wo;
  unsigned short* Wob;
};

__global__ __launch_bounds__(256) void projfused(PGArgs ga) {
  __shared__ unsigned short SH[17408];   // staging 16384; mode-1 transpose 128x136

  const int z = blockIdx.y;
  const int tid = threadIdx.x;

  if (z == 3) {
    // Wob[o][h*64+dp] = bf16(Wo[o][dp*16+h])
    for (int i = blockIdx.x * 256 + tid; i < DB * DB; i += 256 * 256) {
      int o = i >> 10, cp = i & 1023;
      int src = (o << 10) + ((cp & 63) << 4) + (cp >> 6);
      ga.Wob[i] = f2bf(ga.Wo[src]);
    }
    return;
  }

  unsigned short* Ab = SH;
  unsigned short* Bb = SH + 8192;

  const float* __restrict__ Af = ga.A[z];
  const float* __restrict__ Bf = ga.B[z];
  const int mode = ga.mode[z];

  const int w = tid >> 6, lane = tid & 63;
  const int g = lane >> 4, li = lane & 15;
  const int wm = w >> 1, wn = w & 1;
  const int l = xcd_swz(blockIdx.x, 256);
  const int m0 = (l >> 3) * 128, n0 = (l & 7) * 128;

  const int srow = lane >> 3;          // row within 8-row chunk
  const int sg = (lane & 7) ^ srow;    // swizzled source granule (matches reads)

  f32x4 acc[4][4];
  #pragma unroll
  for (int i = 0; i < 4; ++i)
    #pragma unroll
    for (int j = 0; j < 4; ++j)
      #pragma unroll
      for (int e = 0; e < 4; ++e) acc[i][j][e] = 0.f;

  for (int k0 = 0; k0 < DB; k0 += 64) {
    __syncthreads();
    #pragma unroll
    for (int i = 0; i < 4; ++i) {
      int c = w * 4 + i;
      short8 va = cvt8(Af + (size_t)(m0 + c * 8 + srow) * DB + k0 + sg * 8);
      short8 vb = cvt8(Bf + (size_t)(n0 + c * 8 + srow) * DB + k0 + sg * 8);
      *(short8*)&Ab[c * 512 + lane * 8] = va;
      *(short8*)&Bb[c * 512 + lane * 8] = vb;
    }
    __syncthreads();
    short8 af[4][2], bf[4][2];
    #pragma unroll
    for (int mf = 0; mf < 4; ++mf)
      #pragma unroll
      for (int ks = 0; ks < 2; ++ks)
        af[mf][ks] = *(const short8*)&Ab[(wm * 64 + mf * 16 + li) * 64 +
                                         (((ks * 4 + g) ^ (li & 7)) << 3)];
    #pragma unroll
    for (int nf = 0; nf < 4; ++nf)
      #pragma unroll
      for (int ks = 0; ks < 2; ++ks)
        bf[nf][ks] = *(const short8*)&Bb[(wn * 64 + nf * 16 + li) * 64 +
                                         (((ks * 4 + g) ^ (li & 7)) << 3)];
    __builtin_amdgcn_s_setprio(1);
    #pragma unroll
    for (int ks = 0; ks < 2; ++ks)
      #pragma unroll
      for (int mf = 0; mf < 4; ++mf)
        #pragma unroll
        for (int nf = 0; nf < 4; ++nf)
          acc[mf][nf] = __builtin_amdgcn_mfma_f32_16x16x32_bf16(
              af[mf][ks], bf[nf][ks], acc[mf][nf], 0, 0, 0);
    __builtin_amdgcn_s_setprio(0);
  }

  if (mode == 0) {
    unsigned short* O = ga.O[z];
    #pragma unroll
    for (int mf = 0; mf < 4; ++mf)
      #pragma unroll
      for (int nf = 0; nf < 4; ++nf)
        #pragma unroll
        for (int r = 0; r < 4; ++r) {
          int row = m0 + wm * 64 + mf * 16 + g * 4 + r;
          int col = n0 + wn * 64 + nf * 16 + li;
          int b_ = row >> 11, s_ = row & 2047;
          int h = col >> 6, dp = col & 63;
          O[((size_t)(b_ * NHB + h) * SB + s_) * DHB + dp] = f2bf(acc[mf][nf][r]);
        }
  } else {
    unsigned short* O = ga.O[z];
    __syncthreads();
    #pragma unroll
    for (int mf = 0; mf < 4; ++mf)
      #pragma unroll
      for (int nf = 0; nf < 4; ++nf) {
        short4v pk;
        #pragma unroll
        for (int r = 0; r < 4; ++r) pk[r] = (short)f2bf(acc[mf][nf][r]);
        *(short4v*)&SH[(size_t)(wn * 64 + nf * 16 + li) * 136 +
                       wm * 64 + mf * 16 + g * 4] = pk;
      }
    __syncthreads();
    int c = tid >> 1, rh = tid & 1;
    int col = n0 + c;
    int h = col >> 6, dp = col & 63;
    int b_ = m0 >> 11, s0 = (m0 & 2047) + rh * 64;
    unsigned short* dst = O + ((size_t)(b_ * NHB + h) * DHB + dp) * SB + s0;
    #pragma unroll
    for (int j = 0; j < 8; ++j)
      *(short8*)(dst + j * 8) = *(const short8*)&SH[c * 136 + rh * 64 + j * 8];
  }
}

// ---------------- K2: attention, QBLK=128, dbuf K/V, counted-vmcnt pass 2 ---
__global__ __launch_bounds__(256) void attn_kernel(
    const unsigned short* __restrict__ Qh, const unsigned short* __restrict__ Kh,
    const unsigned short* __restrict__ Vt, const int* __restrict__ valid_len,
    float* __restrict__ attn_out, unsigned short* __restrict__ Mg)
{
  __shared__ unsigned short Kb[2][4096];  // 64 keys x 64 dh, linear+swizzled
  __shared__ unsigned short Vb[2][4096];  // 64 dp x 64 keys, linear+swizzled
  __shared__ unsigned short P[128][72];   // P tiles; later O transpose staging

  const int tid = threadIdx.x;
  const int wave = tid >> 6, lane = tid & 63;
  const int g = lane >> 4, li = lane & 15;
  const int lsw = xcd_swz(blockIdx.x, 512);
  const int xcd = lsw >> 6, j = lsw & 63;
  const int bh = ((j >> 5) << 4) + xcd * 2 + ((j >> 4) & 1);
  const int q0 = (j & 15) * 128;
  const int b_ = bh >> 4;
  const int vl = valid_len[b_];
  const int nkt = min(32, (vl + 63) >> 6);

  const int srow = lane >> 3;
  const int sg = (lane & 7) ^ srow;

  const size_t kbase = (size_t)bh * SB * DHB;
  const size_t vbase = (size_t)bh * DHB * SB;

  // Q fragments direct from global (one-time): wave owns 32 q-rows
  short8 qa[2][2];
  #pragma unroll
  for (int qf = 0; qf < 2; ++qf)
    #pragma unroll
    for (int ks = 0; ks < 2; ++ks)
      qa[qf][ks] = *(const short8*)(
          Qh + ((size_t)bh * SB + q0 + wave * 32 + qf * 16 + li) * DHB +
          ks * 32 + g * 8);

  float lQ[2] = {0.f, 0.f};

  // ---- pass 1: l = sum exp2(s*SC2); dbuf K staging, 1 barrier per tile ----
  {
    const int c = wave * 2;
    gld16(Kh + kbase + (size_t)(c * 8 + srow) * DHB + sg * 8, &Kb[0][c * 512]);
    gld16(Kh + kbase + (size_t)((c + 1) * 8 + srow) * DHB + sg * 8,
          &Kb[0][(c + 1) * 512]);
    int cur = 0;
    for (int kti = 0; kti < nkt; ++kti) {
      __syncthreads();
      if (kti + 1 < nkt) {
        int kn = (kti + 1) * 64;
        gld16(Kh + kbase + (size_t)(kn + c * 8 + srow) * DHB + sg * 8,
              &Kb[cur ^ 1][c * 512]);
        gld16(Kh + kbase + (size_t)(kn + (c + 1) * 8 + srow) * DHB + sg * 8,
              &Kb[cur ^ 1][(c + 1) * 512]);
      }
      const int kt = kti * 64;
      f32x4 sc[2][4];
      #pragma unroll
      for (int qf = 0; qf < 2; ++qf)
        #pragma unroll
        for (int nf = 0; nf < 4; ++nf)
          #pragma unroll
          for (int e = 0; e < 4; ++e) sc[qf][nf][e] = 0.f;
      __builtin_amdgcn_s_setprio(1);
      #pragma unroll
      for (int ks = 0; ks < 2; ++ks)
        #pragma unroll
        for (int nf = 0; nf < 4; ++nf) {
          short8 kbf = *(const short8*)&Kb[cur][(nf * 16 + li) * 64 +
                                               (((ks * 4 + g) ^ (li & 7)) << 3)];
          #pragma unroll
          for (int qf = 0; qf < 2; ++qf)
            sc[qf][nf] = __builtin_amdgcn_mfma_f32_16x16x32_bf16(
                kbf, qa[qf][ks], sc[qf][nf], 0, 0, 0);
        }
      __builtin_amdgcn_s_setprio(0);
      if (kt + 64 <= vl) {
        #pragma unroll
        for (int qf = 0; qf < 2; ++qf) {
          float la = 0.f;
          #pragma unroll
          for (int nf = 0; nf < 4; ++nf)
            #pragma unroll
            for (int r = 0; r < 4; ++r) la += exp2f(sc[qf][nf][r] * SC2);
          lQ[qf] += la;
        }
      } else {
        #pragma unroll
        for (int qf = 0; qf < 2; ++qf) {
          float la = 0.f;
          #pragma unroll
          for (int nf = 0; nf < 4; ++nf)
            #pragma unroll
            for (int r = 0; r < 4; ++r) {
              int key = kt + nf * 16 + g * 4 + r;
              float s2 = (key < vl) ? sc[qf][nf][r] * SC2 : -1.5e6f;
              la += exp2f(s2);
            }
          lQ[qf] += la;
        }
      }
      cur ^= 1;
    }
  }
  __syncthreads();   // all pass-1 reads done before pass-2 staging

  float rlQ[2];
  #pragma unroll
  for (int qf = 0; qf < 2; ++qf) {
    float L = lQ[qf];
    L += __shfl_xor(L, 16);
    L += __shfl_xor(L, 32);
    rlQ[qf] = 1.f / L;
  }

  f32x4 oacc[2][4];
  #pragma unroll
  for (int qf = 0; qf < 2; ++qf)
    #pragma unroll
    for (int nf = 0; nf < 4; ++nf)
      #pragma unroll
      for (int e = 0; e < 4; ++e) oacc[qf][nf][e] = 0.f;

  // ---- pass 2: p, f32x4 attn stores (plain), P->LDS, PV; counted vmcnt ----
  {
    const int c = wave * 2;
    gld16(Kh + kbase + (size_t)(c * 8 + srow) * DHB + sg * 8, &Kb[0][c * 512]);
    gld16(Kh + kbase + (size_t)((c + 1) * 8 + srow) * DHB + sg * 8,
          &Kb[0][(c + 1) * 512]);
    gld16(Vt + vbase + (size_t)(c * 8 + srow) * SB + sg * 8, &Vb[0][c * 512]);
    gld16(Vt + vbase + (size_t)((c + 1) * 8 + srow) * SB + sg * 8,
          &Vb[0][(c + 1) * 512]);
    asm volatile("s_waitcnt vmcnt(0)\n\ts_barrier" ::: "memory");
    int cur = 0;
    for (int kti = 0; kti < nkt; ++kti) {
      if (kti + 1 < nkt) {
        int kn = (kti + 1) * 64;
        gld16(Kh + kbase + (size_t)(kn + c * 8 + srow) * DHB + sg * 8,
              &Kb[cur ^ 1][c * 512]);
        gld16(Kh + kbase + (size_t)(kn + (c + 1) * 8 + srow) * DHB + sg * 8,
              &Kb[cur ^ 1][(c + 1) * 512]);
        gld16(Vt + vbase + (size_t)(c * 8 + srow) * SB + kn + sg * 8,
              &Vb[cur ^ 1][c * 512]);
        gld16(Vt + vbase + (size_t)((c + 1) * 8 + srow) * SB + kn + sg * 8,
              &Vb[cur ^ 1][(c + 1) * 512]);
      }
      const int kt = kti * 64;
      f32x4 sc[2][4];
      #pragma unroll
      for (int qf = 0; qf < 2; ++qf)
        #pragma unroll
        for (int nf = 0; nf < 4; ++nf)
          #pragma unroll
          for (int e = 0; e < 4; ++e) sc[qf][nf][e] = 0.f;
      __builtin_amdgcn_s_setprio(1);
      #pragma unroll
      for (int ks = 0; ks < 2; ++ks)
        #pragma unroll
        for (int nf = 0; nf < 4; ++nf) {
          short8 kbf = *(const short8*)&Kb[cur][(nf * 16 + li) * 64 +
                                               (((ks * 4 + g) ^ (li & 7)) << 3)];
          #pragma unroll
          for (int qf = 0; qf < 2; ++qf)
            sc[qf][nf] = __builtin_amdgcn_mfma_f32_16x16x32_bf16(
                kbf, qa[qf][ks], sc[qf][nf], 0, 0, 0);
        }
      __builtin_amdgcn_s_setprio(0);
      const bool fullt = (kt + 64 <= vl);
      #pragma unroll
      for (int qf = 0; qf < 2; ++qf) {
        const int qrow = q0 + wave * 32 + qf * 16 + li;
        #pragma unroll
        for (int nf = 0; nf < 4; ++nf) {
          short4v pk;
          if (fullt) {
            #pragma unroll
            for (int r = 0; r < 4; ++r) {
              float p = exp2f(sc[qf][nf][r] * SC2) * rlQ[qf];
              sc[qf][nf][r] = p;
              pk[r] = (short)f2bf(p);
            }
          } else {
            #pragma unroll
            for (int r = 0; r < 4; ++r) {
              int key = kt + nf * 16 + g * 4 + r;
              float s2 = (key < vl) ? sc[qf][nf][r] * SC2 : -1.5e6f;
              float p = exp2f(s2) * rlQ[qf];
              sc[qf][nf][r] = p;
              pk[r] = (short)f2bf(p);
            }
          }
          *(f32x4*)(attn_out + (size_t)bh * SB * SB + (size_t)qrow * SB +
                    kt + nf * 16 + g * 4) = sc[qf][nf];
          *(short4v*)&P[wave * 32 + qf * 16 + li][nf * 16 + g * 4] = pk;
        }
      }
      __builtin_amdgcn_s_setprio(1);
      #pragma unroll
      for (int ks = 0; ks < 2; ++ks) {
        short8 vbf[4];
        #pragma unroll
        for (int nf = 0; nf < 4; ++nf)
          vbf[nf] = *(const short8*)&Vb[cur][(nf * 16 + li) * 64 +
                                            (((ks * 4 + g) ^ (li & 7)) << 3)];
        #pragma unroll
        for (int qf = 0; qf < 2; ++qf) {
          short8 pa = *(const short8*)&P[wave * 32 + qf * 16 + li][ks * 32 + g * 8];
          #pragma unroll
          for (int nf = 0; nf < 4; ++nf)
            oacc[qf][nf] = __builtin_amdgcn_mfma_f32_16x16x32_bf16(
                pa, vbf[nf], oacc[qf][nf], 0, 0, 0);
        }
      }
      __builtin_amdgcn_s_setprio(0);
      asm volatile("s_waitcnt vmcnt(8)\n\ts_barrier" ::: "memory");
      cur ^= 1;
    }
  }

  // ---- zero-fill the masked tail of this block's 128 attn rows (NT) ----
  {
    int c0 = nkt * 64;
    int rem4 = (SB - c0) >> 2;
    if (rem4 > 0) {
      f32x4 z;
      z[0] = 0.f; z[1] = 0.f; z[2] = 0.f; z[3] = 0.f;
      for (int row = 0; row < 128; ++row) {
        float* dst = attn_out + (size_t)bh * SB * SB + (size_t)(q0 + row) * SB + c0;
        for (int c = tid; c < rem4; c += 256)
          __builtin_nontemporal_store(z, (f32x4*)dst + c);
      }
    }
  }

  // ---- epilogue: O -> LDS transpose -> coalesced head-major Mg stores ----
  __syncthreads();
  const int h = bh & 15;
  #pragma unroll
  for (int qf = 0; qf < 2; ++qf)
    #pragma unroll
    for (int nf = 0; nf < 4; ++nf)
      #pragma unroll
      for (int r = 0; r < 4; ++r)
        P[wave * 32 + qf * 16 + g * 4 + r][nf * 16 + li] = f2bf(oacc[qf][nf][r]);
  __syncthreads();
  {
    int row = tid >> 1, half = (tid & 1) * 32;
    unsigned short* dst = Mg + ((size_t)b_ * SB + q0 + row) * DB + h * 64 + half;
    #pragma unroll
    for (int j2 = 0; j2 < 4; ++j2)
      *(short8*)(dst + j2 * 8) = *(const short8*)&P[row][half + j2 * 8];
  }
}

// ---------------- K3: out = Mg' @ Wob'.T, fp32 out (128x64, 512 blocks) -----
__global__ __launch_bounds__(256) void outproj_kernel(
    const unsigned short* __restrict__ A, const unsigned short* __restrict__ Bw,
    float* __restrict__ Out)
{
  __shared__ unsigned short SH[12288];
  unsigned short* Ab = SH;
  unsigned short* Bb = SH + 8192;

  const int tid = threadIdx.x;
  const int w = tid >> 6, lane = tid & 63;
  const int g = lane >> 4, li = lane & 15;
  const int wm = w >> 1, wn = w & 1;
  const int l = xcd_swz(blockIdx.x, 512);
  const int m0 = (l >> 4) * 128, n0 = (l & 15) * 64;

  const int srow = lane >> 3;
  const int sg = (lane & 7) ^ srow;

  int a_off[4][2], b_off[2][2];
  #pragma unroll
  for (int mf = 0; mf < 4; ++mf) {
    int row = wm * 64 + mf * 16 + li;
    #pragma unroll
    for (int ks = 0; ks < 2; ++ks)
      a_off[mf][ks] = row * 64 + (((ks * 4 + g) ^ (li & 7)) << 3);
  }
  #pragma unroll
  for (int nf = 0; nf < 2; ++nf) {
    int row = wn * 32 + nf * 16 + li;
    #pragma unroll
    for (int ks = 0; ks < 2; ++ks)
      b_off[nf][ks] = row * 64 + (((ks * 4 + g) ^ (li & 7)) << 3);
  }

  f32x4 acc[4][2];
  #pragma unroll
  for (int i = 0; i < 4; ++i)
    #pragma unroll
    for (int j = 0; j < 2; ++j)
      #pragma unroll
      for (int e = 0; e < 4; ++e) acc[i][j][e] = 0.f;

  for (int k0 = 0; k0 < DB; k0 += 64) {
    __syncthreads();
    #pragma unroll
    for (int i = 0; i < 4; ++i) {
      int c = w * 4 + i;
      gld16(A + (size_t)(m0 + c * 8 + srow) * DB + k0 + sg * 8, Ab + c * 512);
    }
    #pragma unroll
    for (int i = 0; i < 2; ++i) {
      int c = w * 2 + i;
      gld16(Bw + (size_t)(n0 + c * 8 + srow) * DB + k0 + sg * 8, Bb + c * 512);
    }
    __syncthreads();
    short8 af[4][2], bf[2][2];
    #pragma unroll
    for (int mf = 0; mf < 4; ++mf)
      #pragma unroll
      for (int ks = 0; ks < 2; ++ks)
        af[mf][ks] = *(const short8*)&Ab[a_off[mf][ks]];
    #pragma unroll
    for (int nf = 0; nf < 2; ++nf)
      #pragma unroll
      for (int ks = 0; ks < 2; ++ks)
        bf[nf][ks] = *(const short8*)&Bb[b_off[nf][ks]];
    __builtin_amdgcn_s_setprio(1);
    #pragma unroll
    for (int ks = 0; ks < 2; ++ks)
      #pragma unroll
      for (int mf = 0; mf < 4; ++mf)
        #pragma unroll
        for (int nf = 0; nf < 2; ++nf)
          acc[mf][nf] = __builtin_amdgcn_mfma_f32_16x16x32_bf16(
              af[mf][ks], bf[nf][ks], acc[mf][nf], 0, 0, 0);
    __builtin_amdgcn_s_setprio(0);
  }

  #pragma unroll
  for (int mf = 0; mf < 4; ++mf)
    #pragma unroll
    for (int nf = 0; nf < 2; ++nf)
      #pragma unroll
      for (int r = 0; r < 4; ++r) {
        int row = m0 + wm * 64 + mf * 16 + g * 4 + r;
        int col = n0 + wn * 32 + nf * 16 + li;
        Out[(size_t)row * DB + col] = acc[mf][nf][r];
      }
}

extern "C" void kernel_launch(void* const* d_in, const int* in_sizes, int n_in,
                              void* d_out, int out_size, void* d_ws, size_t ws_size,
                              hipStream_t stream) {
  const float* q  = (const float*)d_in[0];
  const float* k  = (const float*)d_in[1];
  const float* v  = (const float*)d_in[2];
  const float* Wq = (const float*)d_in[3];
  const float* Wk = (const float*)d_in[4];
  const float* Wv = (const float*)d_in[5];
  const float* Wo = (const float*)d_in[6];
  const int* vlen = (const int*)d_in[7];

  const size_t HS = (size_t)2 * NHB * SB * DHB;  // 4,194,304
  const size_t WS = (size_t)DB * DB;             // 1,048,576

  unsigned short* ws = (unsigned short*)d_ws;
  unsigned short* Wob = ws;
  unsigned short* Qh  = Wob + WS;
  unsigned short* Kh  = Qh + HS;
  unsigned short* Vt  = Kh + HS;
  unsigned short* Mg  = Vt + HS;

  float* out  = (float*)d_out;
  float* attn = out + (size_t)2 * SB * DB;

  PGArgs pa;
  pa.A[0] = q;  pa.A[1] = k;  pa.A[2] = v;
  pa.B[0] = Wq; pa.B[1] = Wk; pa.B[2] = Wv;
  pa.O[0] = Qh; pa.O[1] = Kh; pa.O[2] = Vt;
  pa.mode[0] = 0; pa.mode[1] = 0; pa.mode[2] = 1;
  pa.Wo = Wo; pa.Wob = Wob;

  dim3 blk(256);
  projfused<<<dim3(256, 4), blk, 0, stream>>>(pa);
  attn_kernel<<<dim3(512), blk, 0, stream>>>(Qh, Kh, Vt, vlen, attn, Mg);
  outproj_kernel<<<dim3(512), blk, 0, stream>>>(Mg, Wob, out);
}

// Round 16
// 221.153 us; speedup vs baseline: 1.0683x; 1.0683x over previous
//
#include <hip/hip_runtime.h>
#include <stdint.h>

#define SB 2048
#define DB 1024
#define NHB 16
#define DHB 64

typedef __attribute__((ext_vector_type(8))) short short8;
typedef __attribute__((ext_vector_type(4))) short short4v;
typedef __attribute__((ext_vector_type(4))) float f32x4;

// scale 1/8 folded with log2(e): exp(s/8) = exp2(s * 0.125*log2e)
#define SC2 0.18033688011112042f

__device__ __forceinline__ unsigned short f2bf(float f) {
  union { float f; uint32_t u; } v; v.f = f;
  uint32_t u = v.u;
  return (unsigned short)((u + 0x7FFFu + ((u >> 16) & 1u)) >> 16);
}

__device__ __forceinline__ void gld16(const void* g, void* l) {
  __builtin_amdgcn_global_load_lds(
      (const __attribute__((address_space(1))) void*)g,
      (__attribute__((address_space(3))) void*)l, 16, 0, 0);
}

__device__ __forceinline__ int xcd_swz(int bid, int nwg) {
  return (bid & 7) * (nwg >> 3) + (bid >> 3);   // bijective when nwg % 8 == 0
}

// ---- K0: fp32 -> bf16 convert (6 tensors) + Wo column-permute (y==6) ------
struct ConvArgs {
  const float* s[6];
  unsigned short* d[6];
  int n[6];
};

__global__ __launch_bounds__(256) void conv_kernel(ConvArgs a,
                                                   const float* __restrict__ Wo,
                                                   unsigned short* __restrict__ Wob) {
  const int t = blockIdx.y;
  if (t == 6) {
    // Wob[o][h*64+dp] = bf16(Wo[o][dp*16+h])
    for (int i = blockIdx.x * 256 + threadIdx.x; i < DB * DB; i += gridDim.x * 256) {
      int o = i >> 10, cp = i & 1023;
      int src = (o << 10) + ((cp & 63) << 4) + (cp >> 6);
      Wob[i] = f2bf(Wo[src]);
    }
    return;
  }
  const float* __restrict__ src = a.s[t];
  unsigned short* __restrict__ dst = a.d[t];
  const int n8 = a.n[t] >> 3;
  for (int i = blockIdx.x * 256 + threadIdx.x; i < n8; i += gridDim.x * 256) {
    const f32x4* p = (const f32x4*)src + (size_t)i * 2;
    f32x4 x = p[0], y = p[1];
    short8 o;
    o[0] = (short)f2bf(x[0]); o[1] = (short)f2bf(x[1]);
    o[2] = (short)f2bf(x[2]); o[3] = (short)f2bf(x[3]);
    o[4] = (short)f2bf(y[0]); o[5] = (short)f2bf(y[1]);
    o[6] = (short)f2bf(y[2]); o[7] = (short)f2bf(y[3]);
    *(short8*)(dst + (size_t)i * 8) = o;
  }
}

// ---------------- K1: 128x128 proj GEMM (bf16 in), BK=64, 4 waves 2x2 ------
struct GemmArgs {
  const unsigned short* A[3];
  const unsigned short* B[3];
  void* O[3];
  int mode[3];
};

__global__ __launch_bounds__(256) void gemm128(GemmArgs ga) {
  __shared__ unsigned short SH[17408];   // staging 16384; mode-1 transpose 128x136
  unsigned short* Ab = SH;
  unsigned short* Bb = SH + 8192;

  const int z = blockIdx.y;
  const unsigned short* __restrict__ A = ga.A[z];
  const unsigned short* __restrict__ Bw = ga.B[z];
  const int mode = ga.mode[z];

  const int tid = threadIdx.x;
  const int w = tid >> 6, lane = tid & 63;
  const int g = lane >> 4, li = lane & 15;
  const int wm = w >> 1, wn = w & 1;
  const int l = xcd_swz(blockIdx.x, 256);
  const int m0 = (l >> 3) * 128, n0 = (l & 7) * 128;

  const int srow = lane >> 3;          // row within 8-row chunk
  const int sg = (lane & 7) ^ srow;    // inverse-swizzled source granule

  f32x4 acc[4][4];
  #pragma unroll
  for (int i = 0; i < 4; ++i)
    #pragma unroll
    for (int j = 0; j < 4; ++j)
      #pragma unroll
      for (int e = 0; e < 4; ++e) acc[i][j][e] = 0.f;

  for (int k0 = 0; k0 < DB; k0 += 64) {
    __syncthreads();
    #pragma unroll
    for (int i = 0; i < 4; ++i) {
      int c = w * 4 + i;
      gld16(A + (size_t)(m0 + c * 8 + srow) * DB + k0 + sg * 8, Ab + c * 512);
      gld16(Bw + (size_t)(n0 + c * 8 + srow) * DB + k0 + sg * 8, Bb + c * 512);
    }
    __syncthreads();
    short8 af[4][2], bf[4][2];
    #pragma unroll
    for (int mf = 0; mf < 4; ++mf)
      #pragma unroll
      for (int ks = 0; ks < 2; ++ks)
        af[mf][ks] = *(const short8*)&Ab[(wm * 64 + mf * 16 + li) * 64 +
                                         (((ks * 4 + g) ^ (li & 7)) << 3)];
    #pragma unroll
    for (int nf = 0; nf < 4; ++nf)
      #pragma unroll
      for (int ks = 0; ks < 2; ++ks)
        bf[nf][ks] = *(const short8*)&Bb[(wn * 64 + nf * 16 + li) * 64 +
                                         (((ks * 4 + g) ^ (li & 7)) << 3)];
    __builtin_amdgcn_s_setprio(1);
    #pragma unroll
    for (int ks = 0; ks < 2; ++ks)
      #pragma unroll
      for (int mf = 0; mf < 4; ++mf)
        #pragma unroll
        for (int nf = 0; nf < 4; ++nf)
          acc[mf][nf] = __builtin_amdgcn_mfma_f32_16x16x32_bf16(
              af[mf][ks], bf[nf][ks], acc[mf][nf], 0, 0, 0);
    __builtin_amdgcn_s_setprio(0);
  }

  if (mode == 0) {
    unsigned short* O = (unsigned short*)ga.O[z];
    #pragma unroll
    for (int mf = 0; mf < 4; ++mf)
      #pragma unroll
      for (int nf = 0; nf < 4; ++nf)
        #pragma unroll
        for (int r = 0; r < 4; ++r) {
          int row = m0 + wm * 64 + mf * 16 + g * 4 + r;
          int col = n0 + wn * 64 + nf * 16 + li;
          int b_ = row >> 11, s_ = row & 2047;
          int h = col >> 6, dp = col & 63;
          O[((size_t)(b_ * NHB + h) * SB + s_) * DHB + dp] = f2bf(acc[mf][nf][r]);
        }
  } else {
    unsigned short* O = (unsigned short*)ga.O[z];
    __syncthreads();
    #pragma unroll
    for (int mf = 0; mf < 4; ++mf)
      #pragma unroll
      for (int nf = 0; nf < 4; ++nf) {
        short4v pk;
        #pragma unroll
        for (int r = 0; r < 4; ++r) pk[r] = (short)f2bf(acc[mf][nf][r]);
        *(short4v*)&SH[(size_t)(wn * 64 + nf * 16 + li) * 136 +
                       wm * 64 + mf * 16 + g * 4] = pk;
      }
    __syncthreads();
    int c = tid >> 1, rh = tid & 1;
    int col = n0 + c;
    int h = col >> 6, dp = col & 63;
    int b_ = m0 >> 11, s0 = (m0 & 2047) + rh * 64;
    unsigned short* dst = O + ((size_t)(b_ * NHB + h) * DHB + dp) * SB + s0;
    #pragma unroll
    for (int j = 0; j < 8; ++j)
      *(short8*)(dst + j * 8) = *(const short8*)&SH[c * 136 + rh * 64 + j * 8];
  }
}

// ---------------- K2: attention, QBLK=128, dbuf K/V, counted-vmcnt pass 2 ---
__global__ __launch_bounds__(256) void attn_kernel(
    const unsigned short* __restrict__ Qh, const unsigned short* __restrict__ Kh,
    const unsigned short* __restrict__ Vt, const int* __restrict__ valid_len,
    float* __restrict__ attn_out, unsigned short* __restrict__ Mg)
{
  __shared__ unsigned short Kb[2][4096];  // 64 keys x 64 dh, linear+swizzled
  __shared__ unsigned short Vb[2][4096];  // 64 dp x 64 keys, linear+swizzled
  __shared__ unsigned short P[128][72];   // P tiles; later O transpose staging

  const int tid = threadIdx.x;
  const int wave = tid >> 6, lane = tid & 63;
  const int g = lane >> 4, li = lane & 15;
  const int lsw = xcd_swz(blockIdx.x, 512);
  const int xcd = lsw >> 6, j = lsw & 63;
  const int bh = ((j >> 5) << 4) + xcd * 2 + ((j >> 4) & 1);
  const int q0 = (j & 15) * 128;
  const int b_ = bh >> 4;
  const int vl = valid_len[b_];
  const int nkt = min(32, (vl + 63) >> 6);

  const int srow = lane >> 3;
  const int sg = (lane & 7) ^ srow;

  const size_t kbase = (size_t)bh * SB * DHB;
  const size_t vbase = (size_t)bh * DHB * SB;

  // Q fragments direct from global (one-time): wave owns 32 q-rows
  short8 qa[2][2];
  #pragma unroll
  for (int qf = 0; qf < 2; ++qf)
    #pragma unroll
    for (int ks = 0; ks < 2; ++ks)
      qa[qf][ks] = *(const short8*)(
          Qh + ((size_t)bh * SB + q0 + wave * 32 + qf * 16 + li) * DHB +
          ks * 32 + g * 8);

  float lQ[2] = {0.f, 0.f};

  // ---- pass 1: l = sum exp2(s*SC2); dbuf K staging, 1 barrier per tile ----
  {
    const int c = wave * 2;
    gld16(Kh + kbase + (size_t)(c * 8 + srow) * DHB + sg * 8, &Kb[0][c * 512]);
    gld16(Kh + kbase + (size_t)((c + 1) * 8 + srow) * DHB + sg * 8,
          &Kb[0][(c + 1) * 512]);
    int cur = 0;
    for (int kti = 0; kti < nkt; ++kti) {
      __syncthreads();
      if (kti + 1 < nkt) {
        int kn = (kti + 1) * 64;
        gld16(Kh + kbase + (size_t)(kn + c * 8 + srow) * DHB + sg * 8,
              &Kb[cur ^ 1][c * 512]);
        gld16(Kh + kbase + (size_t)(kn + (c + 1) * 8 + srow) * DHB + sg * 8,
              &Kb[cur ^ 1][(c + 1) * 512]);
      }
      const int kt = kti * 64;
      f32x4 sc[2][4];
      #pragma unroll
      for (int qf = 0; qf < 2; ++qf)
        #pragma unroll
        for (int nf = 0; nf < 4; ++nf)
          #pragma unroll
          for (int e = 0; e < 4; ++e) sc[qf][nf][e] = 0.f;
      __builtin_amdgcn_s_setprio(1);
      #pragma unroll
      for (int ks = 0; ks < 2; ++ks)
        #pragma unroll
        for (int nf = 0; nf < 4; ++nf) {
          short8 kbf = *(const short8*)&Kb[cur][(nf * 16 + li) * 64 +
                                               (((ks * 4 + g) ^ (li & 7)) << 3)];
          #pragma unroll
          for (int qf = 0; qf < 2; ++qf)
            sc[qf][nf] = __builtin_amdgcn_mfma_f32_16x16x32_bf16(
                kbf, qa[qf][ks], sc[qf][nf], 0, 0, 0);
        }
      __builtin_amdgcn_s_setprio(0);
      if (kt + 64 <= vl) {
        #pragma unroll
        for (int qf = 0; qf < 2; ++qf) {
          float la = 0.f;
          #pragma unroll
          for (int nf = 0; nf < 4; ++nf)
            #pragma unroll
            for (int r = 0; r < 4; ++r) la += exp2f(sc[qf][nf][r] * SC2);
          lQ[qf] += la;
        }
      } else {
        #pragma unroll
        for (int qf = 0; qf < 2; ++qf) {
          float la = 0.f;
          #pragma unroll
          for (int nf = 0; nf < 4; ++nf)
            #pragma unroll
            for (int r = 0; r < 4; ++r) {
              int key = kt + nf * 16 + g * 4 + r;
              float s2 = (key < vl) ? sc[qf][nf][r] * SC2 : -1.5e6f;
              la += exp2f(s2);
            }
          lQ[qf] += la;
        }
      }
      cur ^= 1;
    }
  }
  __syncthreads();   // all pass-1 reads done before pass-2 staging

  float rlQ[2];
  #pragma unroll
  for (int qf = 0; qf < 2; ++qf) {
    float L = lQ[qf];
    L += __shfl_xor(L, 16);
    L += __shfl_xor(L, 32);
    rlQ[qf] = 1.f / L;
  }

  f32x4 oacc[2][4];
  #pragma unroll
  for (int qf = 0; qf < 2; ++qf)
    #pragma unroll
    for (int nf = 0; nf < 4; ++nf)
      #pragma unroll
      for (int e = 0; e < 4; ++e) oacc[qf][nf][e] = 0.f;

  // ---- pass 2: p, f32x4 attn stores (plain), P->LDS, PV; counted vmcnt ----
  {
    const int c = wave * 2;
    gld16(Kh + kbase + (size_t)(c * 8 + srow) * DHB + sg * 8, &Kb[0][c * 512]);
    gld16(Kh + kbase + (size_t)((c + 1) * 8 + srow) * DHB + sg * 8,
          &Kb[0][(c + 1) * 512]);
    gld16(Vt + vbase + (size_t)(c * 8 + srow) * SB + sg * 8, &Vb[0][c * 512]);
    gld16(Vt + vbase + (size_t)((c + 1) * 8 + srow) * SB + sg * 8,
          &Vb[0][(c + 1) * 512]);
    asm volatile("s_waitcnt vmcnt(0)\n\ts_barrier" ::: "memory");
    int cur = 0;
    for (int kti = 0; kti < nkt; ++kti) {
      if (kti + 1 < nkt) {
        int kn = (kti + 1) * 64;
        gld16(Kh + kbase + (size_t)(kn + c * 8 + srow) * DHB + sg * 8,
              &Kb[cur ^ 1][c * 512]);
        gld16(Kh + kbase + (size_t)(kn + (c + 1) * 8 + srow) * DHB + sg * 8,
              &Kb[cur ^ 1][(c + 1) * 512]);
        gld16(Vt + vbase + (size_t)(c * 8 + srow) * SB + kn + sg * 8,
              &Vb[cur ^ 1][c * 512]);
        gld16(Vt + vbase + (size_t)((c + 1) * 8 + srow) * SB + kn + sg * 8,
              &Vb[cur ^ 1][(c + 1) * 512]);
      }
      const int kt = kti * 64;
      f32x4 sc[2][4];
      #pragma unroll
      for (int qf = 0; qf < 2; ++qf)
        #pragma unroll
        for (int nf = 0; nf < 4; ++nf)
          #pragma unroll
          for (int e = 0; e < 4; ++e) sc[qf][nf][e] = 0.f;
      __builtin_amdgcn_s_setprio(1);
      #pragma unroll
      for (int ks = 0; ks < 2; ++ks)
        #pragma unroll
        for (int nf = 0; nf < 4; ++nf) {
          short8 kbf = *(const short8*)&Kb[cur][(nf * 16 + li) * 64 +
                                               (((ks * 4 + g) ^ (li & 7)) << 3)];
          #pragma unroll
          for (int qf = 0; qf < 2; ++qf)
            sc[qf][nf] = __builtin_amdgcn_mfma_f32_16x16x32_bf16(
                kbf, qa[qf][ks], sc[qf][nf], 0, 0, 0);
        }
      __builtin_amdgcn_s_setprio(0);
      const bool fullt = (kt + 64 <= vl);
      #pragma unroll
      for (int qf = 0; qf < 2; ++qf) {
        const int qrow = q0 + wave * 32 + qf * 16 + li;
        #pragma unroll
        for (int nf = 0; nf < 4; ++nf) {
          short4v pk;
          if (fullt) {
            #pragma unroll
            for (int r = 0; r < 4; ++r) {
              float p = exp2f(sc[qf][nf][r] * SC2) * rlQ[qf];
              sc[qf][nf][r] = p;
              pk[r] = (short)f2bf(p);
            }
          } else {
            #pragma unroll
            for (int r = 0; r < 4; ++r) {
              int key = kt + nf * 16 + g * 4 + r;
              float s2 = (key < vl) ? sc[qf][nf][r] * SC2 : -1.5e6f;
              float p = exp2f(s2) * rlQ[qf];
              sc[qf][nf][r] = p;
              pk[r] = (short)f2bf(p);
            }
          }
          *(f32x4*)(attn_out + (size_t)bh * SB * SB + (size_t)qrow * SB +
                    kt + nf * 16 + g * 4) = sc[qf][nf];
          *(short4v*)&P[wave * 32 + qf * 16 + li][nf * 16 + g * 4] = pk;
        }
      }
      __builtin_amdgcn_s_setprio(1);
      #pragma unroll
      for (int ks = 0; ks < 2; ++ks) {
        short8 vbf[4];
        #pragma unroll
        for (int nf = 0; nf < 4; ++nf)
          vbf[nf] = *(const short8*)&Vb[cur][(nf * 16 + li) * 64 +
                                            (((ks * 4 + g) ^ (li & 7)) << 3)];
        #pragma unroll
        for (int qf = 0; qf < 2; ++qf) {
          short8 pa = *(const short8*)&P[wave * 32 + qf * 16 + li][ks * 32 + g * 8];
          #pragma unroll
          for (int nf = 0; nf < 4; ++nf)
            oacc[qf][nf] = __builtin_amdgcn_mfma_f32_16x16x32_bf16(
                pa, vbf[nf], oacc[qf][nf], 0, 0, 0);
        }
      }
      __builtin_amdgcn_s_setprio(0);
      asm volatile("s_waitcnt vmcnt(8)\n\ts_barrier" ::: "memory");
      cur ^= 1;
    }
  }

  // ---- zero-fill the masked tail of this block's 128 attn rows (NT) ----
  {
    int c0 = nkt * 64;
    int rem4 = (SB - c0) >> 2;
    if (rem4 > 0) {
      f32x4 z;
      z[0] = 0.f; z[1] = 0.f; z[2] = 0.f; z[3] = 0.f;
      for (int row = 0; row < 128; ++row) {
        float* dst = attn_out + (size_t)bh * SB * SB + (size_t)(q0 + row) * SB + c0;
        for (int c = tid; c < rem4; c += 256)
          __builtin_nontemporal_store(z, (f32x4*)dst + c);
      }
    }
  }

  // ---- epilogue: O -> LDS transpose -> coalesced head-major Mg stores ----
  __syncthreads();
  const int h = bh & 15;
  #pragma unroll
  for (int qf = 0; qf < 2; ++qf)
    #pragma unroll
    for (int nf = 0; nf < 4; ++nf)
      #pragma unroll
      for (int r = 0; r < 4; ++r)
        P[wave * 32 + qf * 16 + g * 4 + r][nf * 16 + li] = f2bf(oacc[qf][nf][r]);
  __syncthreads();
  {
    int row = tid >> 1, half = (tid & 1) * 32;
    unsigned short* dst = Mg + ((size_t)b_ * SB + q0 + row) * DB + h * 64 + half;
    #pragma unroll
    for (int j2 = 0; j2 < 4; ++j2)
      *(short8*)(dst + j2 * 8) = *(const short8*)&P[row][half + j2 * 8];
  }
}

// ---------------- K3: out = Mg' @ Wob'.T, fp32 out (128x64, 512 blocks) -----
__global__ __launch_bounds__(256) void outproj_kernel(
    const unsigned short* __restrict__ A, const unsigned short* __restrict__ Bw,
    float* __restrict__ Out)
{
  __shared__ unsigned short SH[12288];
  unsigned short* Ab = SH;
  unsigned short* Bb = SH + 8192;

  const int tid = threadIdx.x;
  const int w = tid >> 6, lane = tid & 63;
  const int g = lane >> 4, li = lane & 15;
  const int wm = w >> 1, wn = w & 1;
  const int l = xcd_swz(blockIdx.x, 512);
  const int m0 = (l >> 4) * 128, n0 = (l & 15) * 64;

  const int srow = lane >> 3;
  const int sg = (lane & 7) ^ srow;

  int a_off[4][2], b_off[2][2];
  #pragma unroll
  for (int mf = 0; mf < 4; ++mf) {
    int row = wm * 64 + mf * 16 + li;
    #pragma unroll
    for (int ks = 0; ks < 2; ++ks)
      a_off[mf][ks] = row * 64 + (((ks * 4 + g) ^ (li & 7)) << 3);
  }
  #pragma unroll
  for (int nf = 0; nf < 2; ++nf) {
    int row = wn * 32 + nf * 16 + li;
    #pragma unroll
    for (int ks = 0; ks < 2; ++ks)
      b_off[nf][ks] = row * 64 + (((ks * 4 + g) ^ (li & 7)) << 3);
  }

  f32x4 acc[4][2];
  #pragma unroll
  for (int i = 0; i < 4; ++i)
    #pragma unroll
    for (int j = 0; j < 2; ++j)
      #pragma unroll
      for (int e = 0; e < 4; ++e) acc[i][j][e] = 0.f;

  for (int k0 = 0; k0 < DB; k0 += 64) {
    __syncthreads();
    #pragma unroll
    for (int i = 0; i < 4; ++i) {
      int c = w * 4 + i;
      gld16(A + (size_t)(m0 + c * 8 + srow) * DB + k0 + sg * 8, Ab + c * 512);
    }
    #pragma unroll
    for (int i = 0; i < 2; ++i) {
      int c = w * 2 + i;
      gld16(Bw + (size_t)(n0 + c * 8 + srow) * DB + k0 + sg * 8, Bb + c * 512);
    }
    __syncthreads();
    short8 af[4][2], bf[2][2];
    #pragma unroll
    for (int mf = 0; mf < 4; ++mf)
      #pragma unroll
      for (int ks = 0; ks < 2; ++ks)
        af[mf][ks] = *(const short8*)&Ab[a_off[mf][ks]];
    #pragma unroll
    for (int nf = 0; nf < 2; ++nf)
      #pragma unroll
      for (int ks = 0; ks < 2; ++ks)
        bf[nf][ks] = *(const short8*)&Bb[b_off[nf][ks]];
    __builtin_amdgcn_s_setprio(1);
    #pragma unroll
    for (int ks = 0; ks < 2; ++ks)
      #pragma unroll
      for (int mf = 0; mf < 4; ++mf)
        #pragma unroll
        for (int nf = 0; nf < 2; ++nf)
          acc[mf][nf] = __builtin_amdgcn_mfma_f32_16x16x32_bf16(
              af[mf][ks], bf[nf][ks], acc[mf][nf], 0, 0, 0);
    __builtin_amdgcn_s_setprio(0);
  }

  #pragma unroll
  for (int mf = 0; mf < 4; ++mf)
    #pragma unroll
    for (int nf = 0; nf < 2; ++nf)
      #pragma unroll
      for (int r = 0; r < 4; ++r) {
        int row = m0 + wm * 64 + mf * 16 + g * 4 + r;
        int col = n0 + wn * 32 + nf * 16 + li;
        Out[(size_t)row * DB + col] = acc[mf][nf][r];
      }
}

extern "C" void kernel_launch(void* const* d_in, const int* in_sizes, int n_in,
                              void* d_out, int out_size, void* d_ws, size_t ws_size,
                              hipStream_t stream) {
  const float* q  = (const float*)d_in[0];
  const float* k  = (const float*)d_in[1];
  const float* v  = (const float*)d_in[2];
  const float* Wq = (const float*)d_in[3];
  const float* Wk = (const float*)d_in[4];
  const float* Wv = (const float*)d_in[5];
  const float* Wo = (const float*)d_in[6];
  const int* vlen = (const int*)d_in[7];

  const size_t HS = (size_t)2 * NHB * SB * DHB;  // 4,194,304
  const size_t WS = (size_t)DB * DB;             // 1,048,576

  unsigned short* ws = (unsigned short*)d_ws;
  unsigned short* qb  = ws;
  unsigned short* kb  = qb + HS;
  unsigned short* vb  = kb + HS;
  unsigned short* Wqb = vb + HS;
  unsigned short* Wkb = Wqb + WS;
  unsigned short* Wvb = Wkb + WS;
  unsigned short* Wob = Wvb + WS;
  unsigned short* Qh  = Wob + WS;
  unsigned short* Kh  = Qh + HS;
  unsigned short* Vt  = Kh + HS;
  unsigned short* Mg  = qb;   // qb dead after proj; reuse for merged output

  float* out  = (float*)d_out;
  float* attn = out + (size_t)2 * SB * DB;

  ConvArgs ca;
  ca.s[0] = q;  ca.d[0] = qb;  ca.n[0] = (int)HS;
  ca.s[1] = k;  ca.d[1] = kb;  ca.n[1] = (int)HS;
  ca.s[2] = v;  ca.d[2] = vb;  ca.n[2] = (int)HS;
  ca.s[3] = Wq; ca.d[3] = Wqb; ca.n[3] = (int)WS;
  ca.s[4] = Wk; ca.d[4] = Wkb; ca.n[4] = (int)WS;
  ca.s[5] = Wv; ca.d[5] = Wvb; ca.n[5] = (int)WS;

  GemmArgs pa;
  pa.A[0] = qb;  pa.A[1] = kb;  pa.A[2] = vb;
  pa.B[0] = Wqb; pa.B[1] = Wkb; pa.B[2] = Wvb;
  pa.O[0] = Qh;  pa.O[1] = Kh;  pa.O[2] = Vt;
  pa.mode[0] = 0; pa.mode[1] = 0; pa.mode[2] = 1;

  dim3 blk(256);
  conv_kernel<<<dim3(1024, 7), blk, 0, stream>>>(ca, Wo, Wob);
  gemm128<<<dim3(256, 3), blk, 0, stream>>>(pa);
  attn_kernel<<<dim3(512), blk, 0, stream>>>(Qh, Kh, Vt, vlen, attn, Mg);
  outproj_kernel<<<dim3(512), blk, 0, stream>>>(Mg, Wob, out);
}